// Round 1
// baseline (2124.647 us; speedup 1.0000x reference)
//
#include <hip/hip_runtime.h>

// BSPLoss: out = sigma1(f1)^2 + 0.5*(sigma1(f2)^2 + sigma1(f3)^2)
// sigma1^2 = top eigenvalue of G = f^T f (1024x1024 PSD symmetric).
// Method: G = f^T f; 12x trace-normalized squaring (eig-ratio -> ^4096);
//         v = G12*ones, polish v = G12*v; lambda = (v'G0v)/(v'v).
// All fp32; batched over the 3 matrices via blockIdx.z.

#define DIM 1024
#define NROW 8192
#define MSZ (DIM*DIM)
#define NSQUAR 12

// C[i][j] = scale * sum_k A[k*DIM + i] * A[k*DIM + j]   (A^T A, K rows)
// scale = 1/(tr*tr) if trptr else 1. 64x64 tile, 4x4 per thread, BK=32.
__global__ __launch_bounds__(256)
void atb64(const float* __restrict__ a0, const float* __restrict__ a1,
           const float* __restrict__ a2, int K,
           const float* __restrict__ trptr, float* __restrict__ C) {
    const int m = blockIdx.z;
    const float* A = (m == 0) ? a0 : (m == 1 ? a1 : a2);
    float* c = C + (size_t)m * MSZ;
    float scale = 1.0f;
    if (trptr) { float t = trptr[m]; scale = 1.0f / (t * t); }

    __shared__ float As[32][64];
    __shared__ float Bs[32][64];
    const int i0 = blockIdx.y * 64;
    const int j0 = blockIdx.x * 64;
    const int t = threadIdx.x;
    const int tx = t & 15;   // column group (coalesced C writes)
    const int ty = t >> 4;   // row group

    float acc[4][4];
#pragma unroll
    for (int a = 0; a < 4; ++a)
#pragma unroll
        for (int b = 0; b < 4; ++b) acc[a][b] = 0.f;

    for (int k0 = 0; k0 < K; k0 += 32) {
#pragma unroll
        for (int r = 0; r < 8; ++r) {
            int idx = t + r * 256;          // 0..2047
            int kk = idx >> 6;              // 0..31
            int ii = idx & 63;              // 0..63
            const float* row = A + (size_t)(k0 + kk) * DIM;
            As[kk][ii] = row[i0 + ii];      // coalesced (consecutive ii)
            Bs[kk][ii] = row[j0 + ii];
        }
        __syncthreads();
#pragma unroll
        for (int kk = 0; kk < 32; ++kk) {
            float4 av = *(const float4*)&As[kk][ty * 4];  // broadcast in wave
            float4 bv = *(const float4*)&Bs[kk][tx * 4];  // 2-way (free)
            float a4[4] = {av.x, av.y, av.z, av.w};
            float b4[4] = {bv.x, bv.y, bv.z, bv.w};
#pragma unroll
            for (int a = 0; a < 4; ++a)
#pragma unroll
                for (int b = 0; b < 4; ++b) acc[a][b] += a4[a] * b4[b];
        }
        __syncthreads();
    }
#pragma unroll
    for (int a = 0; a < 4; ++a) {
        int i = i0 + ty * 4 + a;
        float4 o = make_float4(acc[a][0] * scale, acc[a][1] * scale,
                               acc[a][2] * scale, acc[a][3] * scale);
        *(float4*)&c[(size_t)i * DIM + j0 + tx * 4] = o;
    }
}

__global__ void trace_k(const float* __restrict__ M, float* __restrict__ tr) {
    int m = blockIdx.x;
    const float* A = M + (size_t)m * MSZ;
    float s = 0.f;
    for (int i = threadIdx.x; i < DIM; i += 256) s += A[(size_t)i * DIM + i];
    for (int off = 32; off; off >>= 1) s += __shfl_down(s, off);
    __shared__ float part[4];
    int lane = threadIdx.x & 63, wv = threadIdx.x >> 6;
    if (lane == 0) part[wv] = s;
    __syncthreads();
    if (threadIdx.x == 0) tr[m] = part[0] + part[1] + part[2] + part[3];
}

// vout[row] = sum_j M[row][j] * (vin ? vin[j] : 1).  One wave per row.
__global__ __launch_bounds__(256)
void matvec_k(const float* __restrict__ M, const float* __restrict__ vin,
              float* __restrict__ vout) {
    int m = blockIdx.y;
    const float* A = M + (size_t)m * MSZ;
    int wv = threadIdx.x >> 6, lane = threadIdx.x & 63;
    int row = blockIdx.x * 4 + wv;
    const float* a = A + (size_t)row * DIM;
    float s = 0.f;
    if (vin) {
        const float* v = vin + m * DIM;
        for (int j = lane; j < DIM; j += 64) s += a[j] * v[j];
    } else {
        for (int j = lane; j < DIM; j += 64) s += a[j];
    }
    for (int off = 32; off; off >>= 1) s += __shfl_down(s, off);
    if (lane == 0) vout[m * DIM + row] = s;
}

// lam[m] = (v.w)/(v.v)
__global__ void rayleigh_k(const float* __restrict__ v, const float* __restrict__ w,
                           float* __restrict__ lam) {
    int m = blockIdx.x;
    const float* vv = v + m * DIM;
    const float* ww = w + m * DIM;
    float n = 0.f, d = 0.f;
    for (int i = threadIdx.x; i < DIM; i += 256) {
        float a = vv[i], b = ww[i];
        n += a * b;
        d += a * a;
    }
    for (int off = 32; off; off >>= 1) {
        n += __shfl_down(n, off);
        d += __shfl_down(d, off);
    }
    __shared__ float pn[4], pd[4];
    int lane = threadIdx.x & 63, wv = threadIdx.x >> 6;
    if (lane == 0) { pn[wv] = n; pd[wv] = d; }
    __syncthreads();
    if (threadIdx.x == 0) {
        float nn = pn[0] + pn[1] + pn[2] + pn[3];
        float dd = pd[0] + pd[1] + pd[2] + pd[3];
        lam[m] = nn / dd;
    }
}

__global__ void combine_k(const float* __restrict__ lam, float* __restrict__ out) {
    if (threadIdx.x == 0 && blockIdx.x == 0)
        out[0] = lam[0] + 0.5f * (lam[1] + lam[2]);
}

extern "C" void kernel_launch(void* const* d_in, const int* in_sizes, int n_in,
                              void* d_out, int out_size, void* d_ws, size_t ws_size,
                              hipStream_t stream) {
    const float* f0 = (const float*)d_in[0];
    const float* f1 = (const float*)d_in[1];
    const float* f2 = (const float*)d_in[2];

    float* ws  = (float*)d_ws;
    float* G0  = ws;                        // 3 * 4 MB  (original Gram, kept for Rayleigh)
    float* P   = ws + (size_t)3 * MSZ;      // ping
    float* Q   = ws + (size_t)6 * MSZ;      // pong
    float* tr  = ws + (size_t)9 * MSZ;      // 3 floats (+pad)
    float* v   = tr + 4;                    // 3 * 1024
    float* w   = v + 3 * DIM;               // 3 * 1024
    float* lam = w + 3 * DIM;               // 3

    dim3 g(16, 16, 3), b(256, 1, 1);

    // G0 = f^T f
    atb64<<<g, b, 0, stream>>>(f0, f1, f2, NROW, nullptr, G0);

    // 12x: dst = (src / tr(src))^2   (symmetric => A^T A == A*A)
    const float* src = G0;
    float* dst = P;
    for (int s = 0; s < NSQUAR; ++s) {
        trace_k<<<3, 256, 0, stream>>>(src, tr);
        atb64<<<g, b, 0, stream>>>(src, src + MSZ, src + 2 * MSZ, DIM, tr, dst);
        src = dst;
        dst = (dst == P) ? Q : P;
    }

    dim3 gm(DIM / 4, 3, 1);
    matvec_k<<<gm, b, 0, stream>>>(src, nullptr, v);  // v = M * ones
    matvec_k<<<gm, b, 0, stream>>>(src, v, w);        // w = M * v   (polish)
    matvec_k<<<gm, b, 0, stream>>>(G0, w, v);         // v = G0 * w
    rayleigh_k<<<3, 256, 0, stream>>>(w, v, lam);     // lam = (w.G0w)/(w.w)
    combine_k<<<1, 64, 0, stream>>>(lam, (float*)d_out);
}

// Round 2
// 595.935 us; speedup vs baseline: 3.5652x; 3.5652x over previous
//
#include <hip/hip_runtime.h>

// BSPLoss: out = sig1(f1)^2 + 0.5*(sig1(f2)^2 + sig1(f3)^2), f: 8192x1024 fp32.
// sig1^2 = top eig of G = f'f. Heavy compute in bf16 MFMA (eigvector only);
// final lambda = |f w|^2 / |w|^2 in fp32 (exact Rayleigh vs original f).

#define DIM 1024
#define NROW 8192
#define MSZ (DIM*DIM)
#define NS 10

typedef __attribute__((ext_vector_type(8))) short short8;
typedef __attribute__((ext_vector_type(4))) float f32x4;

__device__ inline float bf2f(unsigned short u) {
    union { unsigned i; float f; } x; x.i = ((unsigned)u) << 16; return x.f;
}
__device__ inline unsigned short f2bf(float f) {
    union { float f; unsigned i; } x; x.f = f;
    unsigned r = x.i + 0x7FFFu + ((x.i >> 16) & 1u);
    return (unsigned short)(r >> 16);
}
__device__ inline void gload16(const void* g, void* l) {
    __builtin_amdgcn_global_load_lds(
        (const __attribute__((address_space(1))) unsigned int*)g,
        (__attribute__((address_space(3))) unsigned int*)l, 16, 0, 0);
}

__global__ void zero_k(float* p, int n) {
    int i = blockIdx.x * 64 + threadIdx.x;
    if (i < n) p[i] = 0.f;
}

// f fp32 [NROW][DIM] -> ft bf16 [DIM][NROW] (transposed), per matrix m.
__global__ __launch_bounds__(256)
void tconv_k(const float* __restrict__ f0, const float* __restrict__ f1,
             const float* __restrict__ f2, unsigned short* __restrict__ ft) {
    const int m = blockIdx.z;
    const float* f = (m == 0) ? f0 : (m == 1 ? f1 : f2);
    unsigned short* o = ft + (size_t)m * DIM * NROW;
    __shared__ unsigned short T[64][65];
    const int c0 = blockIdx.x * 64, r0 = blockIdx.y * 64;
    const int tid = threadIdx.x;
    const int cx = (tid & 15) * 4, ry = tid >> 4;
#pragma unroll
    for (int i = 0; i < 4; ++i) {
        int r = ry + i * 16;
        float4 v = *(const float4*)&f[(size_t)(r0 + r) * DIM + c0 + cx];
        T[cx + 0][r] = f2bf(v.x);
        T[cx + 1][r] = f2bf(v.y);
        T[cx + 2][r] = f2bf(v.z);
        T[cx + 3][r] = f2bf(v.w);
    }
    __syncthreads();
#pragma unroll
    for (int i = 0; i < 4; ++i) {
        int c = ry + i * 16;
        ushort4 u;
        u.x = T[c][cx + 0]; u.y = T[c][cx + 1];
        u.z = T[c][cx + 2]; u.w = T[c][cx + 3];
        *(ushort4*)&o[(size_t)(c0 + c) * NROW + r0 + cx] = u;
    }
}

// C = S S' over k-contiguous rows: C[i][j] = sum_k S[i][k]*S[j][k].
// S bf16 [DIM][KF] per matrix (mstride elements). Output bf16 * (trin? 1/tr^2 : 1).
// Fused trace of output into trout[m] via diagonal-lane atomics.
// 128x128 tile per block, 4 waves (2x2 of 64x64), BK=32, global_load_lds w16.
__global__ __launch_bounds__(256)
void syrk_mfma(const unsigned short* __restrict__ src, size_t mstride, int KF,
               const float* __restrict__ trin, float* __restrict__ trout,
               unsigned short* __restrict__ dst) {
    const int m = blockIdx.z;
    const unsigned short* S = src + (size_t)m * mstride;
    const int i0 = blockIdx.y * 128, j0 = blockIdx.x * 128;
    const int tid = threadIdx.x, w = tid >> 6, lane = tid & 63;
    const int wi = w >> 1, wj = w & 1;

    __shared__ unsigned short As[128 * 32];
    __shared__ unsigned short Bs[128 * 32];

    f32x4 acc[4][4];
#pragma unroll
    for (int a = 0; a < 4; ++a)
#pragma unroll
        for (int b = 0; b < 4; ++b) acc[a][b] = (f32x4){0.f, 0.f, 0.f, 0.f};

    const int lr = lane >> 2;        // row-within-16 for staging
    const int lc = (lane & 3) * 8;   // k element offset for staging
    const int fr = lane & 15;        // fragment row index
    const int ql = (lane >> 4) * 8;  // fragment k offset

    for (int k0 = 0; k0 < KF; k0 += 32) {
#pragma unroll
        for (int q = 0; q < 2; ++q) {
            int rr = w * 32 + q * 16;
            gload16(S + (size_t)(i0 + rr + lr) * KF + k0 + lc, &As[rr * 32]);
            gload16(S + (size_t)(j0 + rr + lr) * KF + k0 + lc, &Bs[rr * 32]);
        }
        __syncthreads();
        short8 af[4], bfv[4];
#pragma unroll
        for (int a = 0; a < 4; ++a)
            af[a] = *(const short8*)&As[(wi * 64 + a * 16 + fr) * 32 + ql];
#pragma unroll
        for (int b = 0; b < 4; ++b)
            bfv[b] = *(const short8*)&Bs[(wj * 64 + b * 16 + fr) * 32 + ql];
#pragma unroll
        for (int a = 0; a < 4; ++a)
#pragma unroll
            for (int b = 0; b < 4; ++b)
                acc[a][b] = __builtin_amdgcn_mfma_f32_16x16x32_bf16(
                    af[a], bfv[b], acc[a][b], 0, 0, 0);
        __syncthreads();
    }

    float sc = 1.0f;
    if (trin) { float t = trin[m]; sc = 1.0f / (t * t); }
    unsigned short* D = dst + (size_t)m * MSZ;
    const int qr = (lane >> 4) * 4, cn = lane & 15;
#pragma unroll
    for (int a = 0; a < 4; ++a)
#pragma unroll
        for (int b = 0; b < 4; ++b) {
            int col = j0 + wj * 64 + b * 16 + cn;
#pragma unroll
            for (int reg = 0; reg < 4; ++reg) {
                int row = i0 + wi * 64 + a * 16 + qr + reg;
                D[(size_t)row * DIM + col] = f2bf(acc[a][b][reg] * sc);
            }
        }
    // fused trace of the (scaled) output
    if (i0 == j0 && wi == wj) {
        int d = cn - qr;
        if (d >= 0 && d < 4) {
            float s = (acc[0][0][d] + acc[1][1][d] + acc[2][2][d] + acc[3][3][d]) * sc;
            atomicAdd(&trout[m], s);
        }
    }
}

// vout[row] = sum_j M[row][j] * (vin ? vin[j] : 1), M bf16 symmetric.
__global__ __launch_bounds__(256)
void mv_bf16(const unsigned short* __restrict__ M, const float* __restrict__ vin,
             float* __restrict__ vout) {
    int m = blockIdx.y;
    const unsigned short* A = M + (size_t)m * MSZ;
    int wv = threadIdx.x >> 6, lane = threadIdx.x & 63;
    int row = blockIdx.x * 4 + wv;
    const unsigned short* a = A + (size_t)row * DIM;
    float s = 0.f;
    if (vin) {
        const float* v = vin + m * DIM;
        for (int j = lane; j < DIM; j += 64) s += bf2f(a[j]) * v[j];
    } else {
        for (int j = lane; j < DIM; j += 64) s += bf2f(a[j]);
    }
    for (int off = 32; off; off >>= 1) s += __shfl_down(s, off);
    if (lane == 0) vout[m * DIM + row] = s;
}

// u[m][row] = sum_d f[row][d] * w[m][d]   (fp32, one wave per row)
__global__ __launch_bounds__(256)
void rownorm_k(const float* __restrict__ f0, const float* __restrict__ f1,
               const float* __restrict__ f2, const float* __restrict__ w,
               float* __restrict__ u) {
    int m = blockIdx.y;
    const float* f = (m == 0) ? f0 : (m == 1 ? f1 : f2);
    int wv = threadIdx.x >> 6, lane = threadIdx.x & 63;
    int row = blockIdx.x * 4 + wv;
    const float* a = f + (size_t)row * DIM;
    const float* ww = w + m * DIM;
    float s = 0.f;
#pragma unroll
    for (int it = 0; it < 4; ++it) {
        int d = (it * 64 + lane) * 4;
        float4 av = *(const float4*)&a[d];
        float4 bv = *(const float4*)&ww[d];
        s += av.x * bv.x + av.y * bv.y + av.z * bv.z + av.w * bv.w;
    }
    for (int off = 32; off; off >>= 1) s += __shfl_down(s, off);
    if (lane == 0) u[m * NROW + row] = s;
}

// lam[m] = |u_m|^2 / |w_m|^2 ; out = lam0 + 0.5*(lam1+lam2)
__global__ __launch_bounds__(1024)
void final_k(const float* __restrict__ u, const float* __restrict__ w,
             float* __restrict__ out) {
    __shared__ float red[1024];
    int tid = threadIdx.x;
    float lam[3];
    for (int m = 0; m < 3; ++m) {
        float s = 0.f;
        for (int i = tid; i < NROW; i += 1024) { float x = u[m * NROW + i]; s += x * x; }
        red[tid] = s; __syncthreads();
        for (int off = 512; off; off >>= 1) {
            if (tid < off) red[tid] += red[tid + off];
            __syncthreads();
        }
        float num = red[0]; __syncthreads();
        s = 0.f;
        for (int i = tid; i < DIM; i += 1024) { float x = w[m * DIM + i]; s += x * x; }
        red[tid] = s; __syncthreads();
        for (int off = 512; off; off >>= 1) {
            if (tid < off) red[tid] += red[tid + off];
            __syncthreads();
        }
        lam[m] = num / red[0]; __syncthreads();
    }
    if (tid == 0) out[0] = lam[0] + 0.5f * (lam[1] + lam[2]);
}

extern "C" void kernel_launch(void* const* d_in, const int* in_sizes, int n_in,
                              void* d_out, int out_size, void* d_ws, size_t ws_size,
                              hipStream_t stream) {
    const float* f0 = (const float*)d_in[0];
    const float* f1 = (const float*)d_in[1];
    const float* f2 = (const float*)d_in[2];

    char* base = (char*)d_ws;
    unsigned short* ft = (unsigned short*)base;                    // 48 MB bf16 f^T x3
    unsigned short* P  = (unsigned short*)(base + 50331648);       // 6 MB
    unsigned short* Q  = (unsigned short*)(base + 56623104);       // 6 MB
    float* trbuf = (float*)(base + 62914560);                      // (NS+1)*3 <= 64 floats
    float* v = (float*)(base + 62914560 + 256);                    // 3*1024
    float* w = v + 3 * DIM;                                        // 3*1024
    float* u = w + 3 * DIM;                                        // 3*8192

    zero_k<<<1, 64, 0, stream>>>(trbuf, 64);

    dim3 gt(DIM / 64, NROW / 64, 3);
    tconv_k<<<gt, 256, 0, stream>>>(f0, f1, f2, ft);

    dim3 gs(8, 8, 3), b(256, 1, 1);
    // G = ft ft' (K=8192), trace -> trbuf[0..2]
    syrk_mfma<<<gs, b, 0, stream>>>(ft, (size_t)DIM * NROW, NROW,
                                    nullptr, trbuf, P);
    // NS trace-normalized squarings (symmetric => row-major reads are fine)
    unsigned short* cur = P;
    unsigned short* nxt = Q;
    for (int s = 0; s < NS; ++s) {
        syrk_mfma<<<gs, b, 0, stream>>>(cur, (size_t)MSZ, DIM,
                                        trbuf + s * 3, trbuf + (s + 1) * 3, nxt);
        unsigned short* t = cur; cur = nxt; nxt = t;
    }

    dim3 gm(DIM / 4, 3, 1);
    mv_bf16<<<gm, b, 0, stream>>>(cur, nullptr, v);  // v = M*1
    mv_bf16<<<gm, b, 0, stream>>>(cur, v, w);        // w = M*v (polish)

    dim3 gr(NROW / 4, 3, 1);
    rownorm_k<<<gr, b, 0, stream>>>(f0, f1, f2, w, u);  // u = f*w
    final_k<<<1, 1024, 0, stream>>>(u, w, (float*)d_out);
}

// Round 3
// 396.163 us; speedup vs baseline: 5.3631x; 1.5043x over previous
//
#include <hip/hip_runtime.h>

// BSPLoss: out = sig1(f1)^2 + 0.5*(sig1(f2)^2 + sig1(f3)^2), f: 8192x1024 fp32.
// sig1^2 = top eig of G = f'f. bf16 MFMA for G and 8 trace-normalized squarings
// (eigenvector only); final lambda = |f w|^2/|w|^2 in fp32 (scale-invariant).

#define DIM 1024
#define NROW 8192
#define MSZ (DIM*DIM)
#define NS 8

typedef __attribute__((ext_vector_type(8))) short short8;
typedef __attribute__((ext_vector_type(4))) float f32x4;

__device__ inline float bf2f(unsigned short u) {
    union { unsigned i; float f; } x; x.i = ((unsigned)u) << 16; return x.f;
}
__device__ inline unsigned short f2bf(float f) {
    union { float f; unsigned i; } x; x.f = f;
    unsigned r = x.i + 0x7FFFu + ((x.i >> 16) & 1u);
    return (unsigned short)(r >> 16);
}
__device__ inline void gload16(const void* g, void* l) {
    __builtin_amdgcn_global_load_lds(
        (const __attribute__((address_space(1))) unsigned int*)g,
        (__attribute__((address_space(3))) unsigned int*)l, 16, 0, 0);
}

__global__ void zero_k(float* __restrict__ p, int n4) {
    int i = blockIdx.x * 256 + threadIdx.x;
    if (i < n4) ((float4*)p)[i] = make_float4(0.f, 0.f, 0.f, 0.f);
}

// f fp32 [NROW][DIM] -> ft bf16 [DIM][NROW] (transposed), per matrix m.
__global__ __launch_bounds__(256)
void tconv_k(const float* __restrict__ f0, const float* __restrict__ f1,
             const float* __restrict__ f2, unsigned short* __restrict__ ft) {
    const int m = blockIdx.z;
    const float* f = (m == 0) ? f0 : (m == 1 ? f1 : f2);
    unsigned short* o = ft + (size_t)m * DIM * NROW;
    __shared__ unsigned short T[64][65];
    const int c0 = blockIdx.x * 64, r0 = blockIdx.y * 64;
    const int tid = threadIdx.x;
    const int cx = (tid & 15) * 4, ry = tid >> 4;
#pragma unroll
    for (int i = 0; i < 4; ++i) {
        int r = ry + i * 16;
        float4 v = *(const float4*)&f[(size_t)(r0 + r) * DIM + c0 + cx];
        T[cx + 0][r] = f2bf(v.x);
        T[cx + 1][r] = f2bf(v.y);
        T[cx + 2][r] = f2bf(v.z);
        T[cx + 3][r] = f2bf(v.w);
    }
    __syncthreads();
#pragma unroll
    for (int i = 0; i < 4; ++i) {
        int c = ry + i * 16;
        ushort4 u;
        u.x = T[c][cx + 0]; u.y = T[c][cx + 1];
        u.z = T[c][cx + 2]; u.w = T[c][cx + 3];
        *(ushort4*)&o[(size_t)(c0 + c) * NROW + r0 + cx] = u;
    }
}

// Split-K symmetric SYRK: C[i][j] = sum_k S[i][k]S[j][k], upper 128-tiles only,
// fp32 atomicAdd into packed-upper G (36 tiles of 128x128 per matrix).
// grid (36, kc, 3). XOR k-slot swizzle kills ds_read_b128 bank conflicts.
__global__ __launch_bounds__(256)
void syrk_sk(const unsigned short* __restrict__ src, size_t mstride, int KF,
             float* __restrict__ Gp) {
    const int m = blockIdx.z;
    const unsigned short* S = src + (size_t)m * mstride;
    int idx = blockIdx.x, ti = 0;
    while (idx >= 8 - ti) { idx -= 8 - ti; ++ti; }
    const int tj = ti + idx;
    const int i0 = ti * 128, j0 = tj * 128;
    float* G = Gp + ((size_t)m * 36 + blockIdx.x) * 16384;
    const int Kc = KF / gridDim.y;
    const int k0b = blockIdx.y * Kc;

    __shared__ unsigned short As[128 * 32];
    __shared__ unsigned short Bs[128 * 32];

    const int tid = threadIdx.x, w = tid >> 6, lane = tid & 63;
    const int wi = w >> 1, wj = w & 1;

    f32x4 acc[4][4];
#pragma unroll
    for (int a = 0; a < 4; ++a)
#pragma unroll
        for (int b = 0; b < 4; ++b) acc[a][b] = (f32x4){0.f, 0.f, 0.f, 0.f};

    const int lr = lane >> 2;                                    // staging row in 16
    const int ksw = (((lane & 3) ^ ((lane >> 4) & 3)) * 8);      // swizzled k-chunk
    const int fr = lane & 15;                                    // fragment row
    const int slot = (((lane >> 4) ^ ((fr >> 2) & 3)) * 8);      // swizzled read slot

    for (int k0 = k0b; k0 < k0b + Kc; k0 += 32) {
#pragma unroll
        for (int q = 0; q < 2; ++q) {
            int rr = w * 32 + q * 16;
            gload16(S + (size_t)(i0 + rr + lr) * KF + k0 + ksw, &As[rr * 32]);
            gload16(S + (size_t)(j0 + rr + lr) * KF + k0 + ksw, &Bs[rr * 32]);
        }
        __syncthreads();
        short8 af[4], bfv[4];
#pragma unroll
        for (int a = 0; a < 4; ++a)
            af[a] = *(const short8*)&As[(wi * 64 + a * 16 + fr) * 32 + slot];
#pragma unroll
        for (int b = 0; b < 4; ++b)
            bfv[b] = *(const short8*)&Bs[(wj * 64 + b * 16 + fr) * 32 + slot];
#pragma unroll
        for (int a = 0; a < 4; ++a)
#pragma unroll
            for (int b = 0; b < 4; ++b)
                acc[a][b] = __builtin_amdgcn_mfma_f32_16x16x32_bf16(
                    af[a], bfv[b], acc[a][b], 0, 0, 0);
        __syncthreads();
    }

    const int qr = (lane >> 4) * 4, cn = lane & 15;
#pragma unroll
    for (int a = 0; a < 4; ++a)
#pragma unroll
        for (int b = 0; b < 4; ++b) {
            int cl = wj * 64 + b * 16 + cn;
#pragma unroll
            for (int reg = 0; reg < 4; ++reg) {
                int rl = wi * 64 + a * 16 + qr + reg;
                atomicAdd(&G[rl * 128 + cl], acc[a][b][reg]);
            }
        }
}

// Packed-upper fp32 G -> full bf16 matrix (mirror via swizzled LDS transpose),
// fused trace -> trout[m]. grid (36,1,3).
__global__ __launch_bounds__(256)
void convert_k(const float* __restrict__ Gp, float* __restrict__ trout,
               unsigned short* __restrict__ dst) {
    const int m = blockIdx.z;
    int idx = blockIdx.x, ti = 0;
    while (idx >= 8 - ti) { idx -= 8 - ti; ++ti; }
    const int tj = ti + idx;
    const int i0 = ti * 128, j0 = tj * 128;
    const float* G = Gp + ((size_t)m * 36 + blockIdx.x) * 16384;
    unsigned short* D = dst + (size_t)m * MSZ;
    __shared__ unsigned short T[128][136];
    const int tid = threadIdx.x;
    const int cx = (tid & 31) * 4, ry = tid >> 5;
    float dtr = 0.f;
#pragma unroll 4
    for (int t = 0; t < 16; ++t) {
        int r = ry + t * 8;
        float4 g = *(const float4*)&G[r * 128 + cx];
        ushort4 o;
        o.x = f2bf(g.x); o.y = f2bf(g.y); o.z = f2bf(g.z); o.w = f2bf(g.w);
        *(ushort4*)&D[(size_t)(i0 + r) * DIM + j0 + cx] = o;
        int rs = r ^ (cx & 124);   // bank-spread swizzle on second index
        T[cx + 0][rs] = o.x; T[cx + 1][rs] = o.y;
        T[cx + 2][rs] = o.z; T[cx + 3][rs] = o.w;
        if (ti == tj) {
            int d = r - cx;
            if (d >= 0 && d < 4)
                dtr += (d == 0 ? g.x : d == 1 ? g.y : d == 2 ? g.z : g.w);
        }
    }
    if (ti == tj) atomicAdd(&trout[m], dtr);
    if (ti != tj) {
        __syncthreads();
#pragma unroll 4
        for (int t = 0; t < 16; ++t) {
            int p = ry + t * 8;
            int qs = cx ^ (p & 124);
            ushort4 o = *(const ushort4*)&T[p][qs];
            *(ushort4*)&D[(size_t)(j0 + p) * DIM + i0 + cx] = o;
        }
    }
}

// One trace-normalized squaring: dst = (src/tr)^2, symmetric 64-tiles, fused
// scale + mirror + trace. grid (136,1,3).
__global__ __launch_bounds__(256)
void sq64(const unsigned short* __restrict__ src, const float* __restrict__ trin,
          float* __restrict__ trout, unsigned short* __restrict__ dst) {
    const int m = blockIdx.z;
    const unsigned short* S = src + (size_t)m * MSZ;
    unsigned short* D = dst + (size_t)m * MSZ;
    int idx = blockIdx.x, ti = 0;
    while (idx >= 16 - ti) { idx -= 16 - ti; ++ti; }
    const int tj = ti + idx;
    const int i0 = ti * 64, j0 = tj * 64;
    float tv = trin[m];
    const float sc = 1.f / (tv * tv);

    __shared__ unsigned short As[64 * 32];
    __shared__ unsigned short Bs[64 * 32];
    __shared__ unsigned short Ts[64][68];

    const int tid = threadIdx.x, w = tid >> 6, lane = tid & 63;
    const int wi = w >> 1, wj = w & 1;
    f32x4 acc[2][2];
#pragma unroll
    for (int a = 0; a < 2; ++a)
#pragma unroll
        for (int b = 0; b < 2; ++b) acc[a][b] = (f32x4){0.f, 0.f, 0.f, 0.f};

    const int lr = lane >> 2;
    const int ksw = (((lane & 3) ^ ((lane >> 4) & 3)) * 8);
    const int fr = lane & 15;
    const int slot = (((lane >> 4) ^ ((fr >> 2) & 3)) * 8);

    for (int k0 = 0; k0 < DIM; k0 += 32) {
        gload16(S + (size_t)(i0 + w * 16 + lr) * DIM + k0 + ksw, &As[w * 16 * 32]);
        gload16(S + (size_t)(j0 + w * 16 + lr) * DIM + k0 + ksw, &Bs[w * 16 * 32]);
        __syncthreads();
        short8 af[2], bfv[2];
#pragma unroll
        for (int a = 0; a < 2; ++a)
            af[a] = *(const short8*)&As[(wi * 32 + a * 16 + fr) * 32 + slot];
#pragma unroll
        for (int b = 0; b < 2; ++b)
            bfv[b] = *(const short8*)&Bs[(wj * 32 + b * 16 + fr) * 32 + slot];
#pragma unroll
        for (int a = 0; a < 2; ++a)
#pragma unroll
            for (int b = 0; b < 2; ++b)
                acc[a][b] = __builtin_amdgcn_mfma_f32_16x16x32_bf16(
                    af[a], bfv[b], acc[a][b], 0, 0, 0);
        __syncthreads();
    }

    const int qr = (lane >> 4) * 4, cn = lane & 15;
#pragma unroll
    for (int a = 0; a < 2; ++a)
#pragma unroll
        for (int b = 0; b < 2; ++b) {
            int cl = wj * 32 + b * 16 + cn;
#pragma unroll
            for (int reg = 0; reg < 4; ++reg) {
                int rl = wi * 32 + a * 16 + qr + reg;
                unsigned short val = f2bf(acc[a][b][reg] * sc);
                D[(size_t)(i0 + rl) * DIM + j0 + cl] = val;
                Ts[cl][rl] = val;
            }
        }
    if (ti == tj && wi == wj) {
        int d = cn - qr;
        if (d >= 0 && d < 4)
            atomicAdd(&trout[m], (acc[0][0][d] + acc[1][1][d]) * sc);
    }
    if (ti != tj) {
        __syncthreads();
        const int cx = (tid & 15) * 4, ry = tid >> 4;
#pragma unroll
        for (int tq = 0; tq < 4; ++tq) {
            int p = ry + tq * 16;
            ushort4 o;
            o.x = Ts[p][cx + 0]; o.y = Ts[p][cx + 1];
            o.z = Ts[p][cx + 2]; o.w = Ts[p][cx + 3];
            *(ushort4*)&D[(size_t)(j0 + p) * DIM + i0 + cx] = o;
        }
    }
}

// vout[row] = sum_j M[row][j] * (vin ? vin[j] : 1), M bf16 symmetric.
__global__ __launch_bounds__(256)
void mv_bf16(const unsigned short* __restrict__ M, const float* __restrict__ vin,
             float* __restrict__ vout) {
    int m = blockIdx.y;
    const unsigned short* A = M + (size_t)m * MSZ;
    int wv = threadIdx.x >> 6, lane = threadIdx.x & 63;
    int row = blockIdx.x * 4 + wv;
    const unsigned short* a = A + (size_t)row * DIM;
    float s = 0.f;
    if (vin) {
        const float* v = vin + m * DIM;
        for (int j = lane; j < DIM; j += 64) s += bf2f(a[j]) * v[j];
    } else {
        for (int j = lane; j < DIM; j += 64) s += bf2f(a[j]);
    }
    for (int off = 32; off; off >>= 1) s += __shfl_down(s, off);
    if (lane == 0) vout[m * DIM + row] = s;
}

// u[m][row] = sum_d f[row][d] * w[m][d]   (fp32, one wave per row)
__global__ __launch_bounds__(256)
void rownorm_k(const float* __restrict__ f0, const float* __restrict__ f1,
               const float* __restrict__ f2, const float* __restrict__ w,
               float* __restrict__ u) {
    int m = blockIdx.y;
    const float* f = (m == 0) ? f0 : (m == 1 ? f1 : f2);
    int wv = threadIdx.x >> 6, lane = threadIdx.x & 63;
    int row = blockIdx.x * 4 + wv;
    const float* a = f + (size_t)row * DIM;
    const float* ww = w + m * DIM;
    float s = 0.f;
#pragma unroll
    for (int it = 0; it < 4; ++it) {
        int d = (it * 64 + lane) * 4;
        float4 av = *(const float4*)&a[d];
        float4 bv = *(const float4*)&ww[d];
        s += av.x * bv.x + av.y * bv.y + av.z * bv.z + av.w * bv.w;
    }
    for (int off = 32; off; off >>= 1) s += __shfl_down(s, off);
    if (lane == 0) u[m * NROW + row] = s;
}

// lam[m] = |u_m|^2 / |w_m|^2 ; out = lam0 + 0.5*(lam1+lam2)
__global__ __launch_bounds__(1024)
void final_k(const float* __restrict__ u, const float* __restrict__ w,
             float* __restrict__ out) {
    __shared__ float red[1024];
    int tid = threadIdx.x;
    float lam[3];
    for (int m = 0; m < 3; ++m) {
        float s = 0.f;
        for (int i = tid; i < NROW; i += 1024) { float x = u[m * NROW + i]; s += x * x; }
        red[tid] = s; __syncthreads();
        for (int off = 512; off; off >>= 1) {
            if (tid < off) red[tid] += red[tid + off];
            __syncthreads();
        }
        float num = red[0]; __syncthreads();
        s = 0.f;
        for (int i = tid; i < DIM; i += 1024) { float x = w[m * DIM + i]; s += x * x; }
        red[tid] = s; __syncthreads();
        for (int off = 512; off; off >>= 1) {
            if (tid < off) red[tid] += red[tid + off];
            __syncthreads();
        }
        lam[m] = num / red[0]; __syncthreads();
    }
    if (tid == 0) out[0] = lam[0] + 0.5f * (lam[1] + lam[2]);
}

extern "C" void kernel_launch(void* const* d_in, const int* in_sizes, int n_in,
                              void* d_out, int out_size, void* d_ws, size_t ws_size,
                              hipStream_t stream) {
    const float* f0 = (const float*)d_in[0];
    const float* f1 = (const float*)d_in[1];
    const float* f2 = (const float*)d_in[2];

    char* base = (char*)d_ws;
    unsigned short* ft = (unsigned short*)base;                   // 48 MB bf16 f^T x3
    unsigned short* P  = (unsigned short*)(base + 50331648);      // 6 MB bf16 M x3
    float* G32 = (float*)(base + 56623104);                       // 7.08 MB packed-upper fp32
    unsigned short* Q  = (unsigned short*)(base + 56623104);      // overlays G32 (dead after convert)
    float* trbuf = (float*)(base + 63700992);                     // 64 floats
    float* v = (float*)(base + 63701248);                         // 3*1024
    float* w = v + 3 * DIM;                                       // 3*1024
    float* u = w + 3 * DIM;                                       // 3*8192

    // zero G32 (packed, 1769472 floats) + trbuf (64 floats) in one pass
    zero_k<<<1729, 256, 0, stream>>>(G32, 442384);

    dim3 gt(DIM / 64, NROW / 64, 3);
    tconv_k<<<gt, 256, 0, stream>>>(f0, f1, f2, ft);

    // G = ft ft' (K=8192), split-K x8, upper tiles, atomic fp32 accumulate
    syrk_sk<<<dim3(36, 8, 3), 256, 0, stream>>>(ft, (size_t)DIM * NROW, NROW, G32);
    // packed fp32 -> full bf16 P + trace
    convert_k<<<dim3(36, 1, 3), 256, 0, stream>>>(G32, trbuf, P);

    unsigned short* cur = P;
    unsigned short* nxt = Q;
    for (int s = 0; s < NS; ++s) {
        sq64<<<dim3(136, 1, 3), 256, 0, stream>>>(cur, trbuf + s * 3,
                                                  trbuf + (s + 1) * 3, nxt);
        unsigned short* t2 = cur; cur = nxt; nxt = t2;
    }

    dim3 b(256, 1, 1);
    dim3 gm(DIM / 4, 3, 1);
    mv_bf16<<<gm, b, 0, stream>>>(cur, nullptr, v);   // v = M*1
    mv_bf16<<<gm, b, 0, stream>>>(cur, v, w);         // w = M*v (polish)

    dim3 gr(NROW / 4, 3, 1);
    rownorm_k<<<gr, b, 0, stream>>>(f0, f1, f2, w, u);  // u = f*w
    final_k<<<1, 1024, 0, stream>>>(u, w, (float*)d_out);
}

// Round 4
// 337.696 us; speedup vs baseline: 6.2916x; 1.1731x over previous
//
#include <hip/hip_runtime.h>

// BSPLoss: out = sig1(f1)^2 + 0.5*(sig1(f2)^2 + sig1(f3)^2), f: 8192x1024 fp32.
// sig1^2 = top eig of G = f'f. bf16 MFMA for G and 6 trace-normalized squarings
// (eigenvector only); final lambda = |f w|^2/|w|^2 in fp32 (scale-invariant).

#define DIM 1024
#define NROW 8192
#define MSZ (DIM*DIM)
#define NS 6

typedef __attribute__((ext_vector_type(8))) short short8;
typedef __attribute__((ext_vector_type(4))) float f32x4;

__device__ inline float bf2f(unsigned short u) {
    union { unsigned i; float f; } x; x.i = ((unsigned)u) << 16; return x.f;
}
__device__ inline unsigned short f2bf(float f) {
    union { float f; unsigned i; } x; x.f = f;
    unsigned r = x.i + 0x7FFFu + ((x.i >> 16) & 1u);
    return (unsigned short)(r >> 16);
}
__device__ inline void gload16(const void* g, void* l) {
    __builtin_amdgcn_global_load_lds(
        (const __attribute__((address_space(1))) unsigned int*)g,
        (__attribute__((address_space(3))) unsigned int*)l, 16, 0, 0);
}

__global__ void zero_k(float* __restrict__ p, int n4) {
    int i = blockIdx.x * 256 + threadIdx.x;
    if (i < n4) ((float4*)p)[i] = make_float4(0.f, 0.f, 0.f, 0.f);
}

// f fp32 [NROW][DIM] -> ft bf16 [DIM][NROW] (transposed), per matrix m.
__global__ __launch_bounds__(256)
void tconv_k(const float* __restrict__ f0, const float* __restrict__ f1,
             const float* __restrict__ f2, unsigned short* __restrict__ ft) {
    const int m = blockIdx.z;
    const float* f = (m == 0) ? f0 : (m == 1 ? f1 : f2);
    unsigned short* o = ft + (size_t)m * DIM * NROW;
    __shared__ unsigned short T[64][65];
    const int c0 = blockIdx.x * 64, r0 = blockIdx.y * 64;
    const int tid = threadIdx.x;
    const int cx = (tid & 15) * 4, ry = tid >> 4;
#pragma unroll
    for (int i = 0; i < 4; ++i) {
        int r = ry + i * 16;
        float4 v = *(const float4*)&f[(size_t)(r0 + r) * DIM + c0 + cx];
        T[cx + 0][r] = f2bf(v.x);
        T[cx + 1][r] = f2bf(v.y);
        T[cx + 2][r] = f2bf(v.z);
        T[cx + 3][r] = f2bf(v.w);
    }
    __syncthreads();
#pragma unroll
    for (int i = 0; i < 4; ++i) {
        int c = ry + i * 16;
        ushort4 u;
        u.x = T[c][cx + 0]; u.y = T[c][cx + 1];
        u.z = T[c][cx + 2]; u.w = T[c][cx + 3];
        *(ushort4*)&o[(size_t)(c0 + c) * NROW + r0 + cx] = u;
    }
}

// Split-K symmetric SYRK: C[i][j] = sum_k S[i][k]S[j][k], upper 128-tiles only,
// fp32 atomicAdd into packed-upper G (36 tiles of 128x128 per matrix).
// grid (36, 4, 3). BK=64 as two 32-halves (sequential frag reuse, halved
// barrier count). XOR k-slot swizzle keeps ds_read_b128 at its 8-cyc floor.
__global__ __launch_bounds__(256)
void syrk_sk(const unsigned short* __restrict__ src, size_t mstride, int KF,
             float* __restrict__ Gp) {
    const int m = blockIdx.z;
    const unsigned short* S = src + (size_t)m * mstride;
    int idx = blockIdx.x, ti = 0;
    while (idx >= 8 - ti) { idx -= 8 - ti; ++ti; }
    const int tj = ti + idx;
    const int i0 = ti * 128, j0 = tj * 128;
    float* G = Gp + ((size_t)m * 36 + blockIdx.x) * 16384;
    const int Kc = KF / gridDim.y;
    const int k0b = blockIdx.y * Kc;

    __shared__ unsigned short As[2 * 128 * 32];
    __shared__ unsigned short Bs[2 * 128 * 32];

    const int tid = threadIdx.x, w = tid >> 6, lane = tid & 63;
    const int wi = w >> 1, wj = w & 1;

    f32x4 acc[4][4];
#pragma unroll
    for (int a = 0; a < 4; ++a)
#pragma unroll
        for (int b = 0; b < 4; ++b) acc[a][b] = (f32x4){0.f, 0.f, 0.f, 0.f};

    const int lr = lane >> 2;                                    // staging row in 16
    const int ksw = (((lane & 3) ^ ((lane >> 4) & 3)) * 8);      // swizzled k-chunk
    const int fr = lane & 15;                                    // fragment row
    const int slot = (((lane >> 4) ^ ((fr >> 2) & 3)) * 8);      // swizzled read slot

    for (int k0 = k0b; k0 < k0b + Kc; k0 += 64) {
#pragma unroll
        for (int h = 0; h < 2; ++h)
#pragma unroll
            for (int q = 0; q < 2; ++q) {
                int rr = w * 32 + q * 16;
                gload16(S + (size_t)(i0 + rr + lr) * KF + k0 + h * 32 + ksw,
                        &As[h * 4096 + rr * 32]);
                gload16(S + (size_t)(j0 + rr + lr) * KF + k0 + h * 32 + ksw,
                        &Bs[h * 4096 + rr * 32]);
            }
        __syncthreads();
#pragma unroll
        for (int h = 0; h < 2; ++h) {
            short8 af[4], bfv[4];
#pragma unroll
            for (int a = 0; a < 4; ++a)
                af[a] = *(const short8*)&As[h * 4096 + (wi * 64 + a * 16 + fr) * 32 + slot];
#pragma unroll
            for (int b = 0; b < 4; ++b)
                bfv[b] = *(const short8*)&Bs[h * 4096 + (wj * 64 + b * 16 + fr) * 32 + slot];
#pragma unroll
            for (int a = 0; a < 4; ++a)
#pragma unroll
                for (int b = 0; b < 4; ++b)
                    acc[a][b] = __builtin_amdgcn_mfma_f32_16x16x32_bf16(
                        af[a], bfv[b], acc[a][b], 0, 0, 0);
        }
        __syncthreads();
    }

    const int qr = (lane >> 4) * 4, cn = lane & 15;
#pragma unroll
    for (int a = 0; a < 4; ++a)
#pragma unroll
        for (int b = 0; b < 4; ++b) {
            int cl = wj * 64 + b * 16 + cn;
#pragma unroll
            for (int reg = 0; reg < 4; ++reg) {
                int rl = wi * 64 + a * 16 + qr + reg;
                atomicAdd(&G[rl * 128 + cl], acc[a][b][reg]);
            }
        }
}

// Packed-upper fp32 G -> full bf16 matrix (mirror via swizzled LDS transpose),
// fused trace -> trout[m]. grid (36,1,3).
__global__ __launch_bounds__(256)
void convert_k(const float* __restrict__ Gp, float* __restrict__ trout,
               unsigned short* __restrict__ dst) {
    const int m = blockIdx.z;
    int idx = blockIdx.x, ti = 0;
    while (idx >= 8 - ti) { idx -= 8 - ti; ++ti; }
    const int tj = ti + idx;
    const int i0 = ti * 128, j0 = tj * 128;
    const float* G = Gp + ((size_t)m * 36 + blockIdx.x) * 16384;
    unsigned short* D = dst + (size_t)m * MSZ;
    __shared__ unsigned short T[128][136];
    const int tid = threadIdx.x;
    const int cx = (tid & 31) * 4, ry = tid >> 5;
    float dtr = 0.f;
#pragma unroll 4
    for (int t = 0; t < 16; ++t) {
        int r = ry + t * 8;
        float4 g = *(const float4*)&G[r * 128 + cx];
        ushort4 o;
        o.x = f2bf(g.x); o.y = f2bf(g.y); o.z = f2bf(g.z); o.w = f2bf(g.w);
        *(ushort4*)&D[(size_t)(i0 + r) * DIM + j0 + cx] = o;
        int rs = r ^ (cx & 124);   // bank-spread swizzle on second index
        T[cx + 0][rs] = o.x; T[cx + 1][rs] = o.y;
        T[cx + 2][rs] = o.z; T[cx + 3][rs] = o.w;
        if (ti == tj) {
            int d = r - cx;
            if (d >= 0 && d < 4)
                dtr += (d == 0 ? g.x : d == 1 ? g.y : d == 2 ? g.z : g.w);
        }
    }
    if (ti == tj) atomicAdd(&trout[m], dtr);
    if (ti != tj) {
        __syncthreads();
#pragma unroll 4
        for (int t = 0; t < 16; ++t) {
            int p = ry + t * 8;
            int qs = cx ^ (p & 124);
            ushort4 o = *(const ushort4*)&T[p][qs];
            *(ushort4*)&D[(size_t)(j0 + p) * DIM + i0 + cx] = o;
        }
    }
}

// One trace-normalized squaring: dst = (src/tr)^2, symmetric 64-tiles, fused
// scale + mirror + trace. grid (136,1,3).
__global__ __launch_bounds__(256)
void sq64(const unsigned short* __restrict__ src, const float* __restrict__ trin,
          float* __restrict__ trout, unsigned short* __restrict__ dst) {
    const int m = blockIdx.z;
    const unsigned short* S = src + (size_t)m * MSZ;
    unsigned short* D = dst + (size_t)m * MSZ;
    int idx = blockIdx.x, ti = 0;
    while (idx >= 16 - ti) { idx -= 16 - ti; ++ti; }
    const int tj = ti + idx;
    const int i0 = ti * 64, j0 = tj * 64;
    float tv = trin[m];
    const float sc = 1.f / (tv * tv);

    __shared__ unsigned short As[64 * 32];
    __shared__ unsigned short Bs[64 * 32];
    __shared__ unsigned short Ts[64][68];

    const int tid = threadIdx.x, w = tid >> 6, lane = tid & 63;
    const int wi = w >> 1, wj = w & 1;
    f32x4 acc[2][2];
#pragma unroll
    for (int a = 0; a < 2; ++a)
#pragma unroll
        for (int b = 0; b < 2; ++b) acc[a][b] = (f32x4){0.f, 0.f, 0.f, 0.f};

    const int lr = lane >> 2;
    const int ksw = (((lane & 3) ^ ((lane >> 4) & 3)) * 8);
    const int fr = lane & 15;
    const int slot = (((lane >> 4) ^ ((fr >> 2) & 3)) * 8);

    for (int k0 = 0; k0 < DIM; k0 += 32) {
        gload16(S + (size_t)(i0 + w * 16 + lr) * DIM + k0 + ksw, &As[w * 16 * 32]);
        gload16(S + (size_t)(j0 + w * 16 + lr) * DIM + k0 + ksw, &Bs[w * 16 * 32]);
        __syncthreads();
        short8 af[2], bfv[2];
#pragma unroll
        for (int a = 0; a < 2; ++a)
            af[a] = *(const short8*)&As[(wi * 32 + a * 16 + fr) * 32 + slot];
#pragma unroll
        for (int b = 0; b < 2; ++b)
            bfv[b] = *(const short8*)&Bs[(wj * 32 + b * 16 + fr) * 32 + slot];
#pragma unroll
        for (int a = 0; a < 2; ++a)
#pragma unroll
            for (int b = 0; b < 2; ++b)
                acc[a][b] = __builtin_amdgcn_mfma_f32_16x16x32_bf16(
                    af[a], bfv[b], acc[a][b], 0, 0, 0);
        __syncthreads();
    }

    const int qr = (lane >> 4) * 4, cn = lane & 15;
#pragma unroll
    for (int a = 0; a < 2; ++a)
#pragma unroll
        for (int b = 0; b < 2; ++b) {
            int cl = wj * 32 + b * 16 + cn;
#pragma unroll
            for (int reg = 0; reg < 4; ++reg) {
                int rl = wi * 32 + a * 16 + qr + reg;
                unsigned short val = f2bf(acc[a][b][reg] * sc);
                D[(size_t)(i0 + rl) * DIM + j0 + cl] = val;
                Ts[cl][rl] = val;
            }
        }
    if (ti == tj && wi == wj) {
        int d = cn - qr;
        if (d >= 0 && d < 4)
            atomicAdd(&trout[m], (acc[0][0][d] + acc[1][1][d]) * sc);
    }
    if (ti != tj) {
        __syncthreads();
        const int cx = (tid & 15) * 4, ry = tid >> 4;
#pragma unroll
        for (int tq = 0; tq < 4; ++tq) {
            int p = ry + tq * 16;
            ushort4 o;
            o.x = Ts[p][cx + 0]; o.y = Ts[p][cx + 1];
            o.z = Ts[p][cx + 2]; o.w = Ts[p][cx + 3];
            *(ushort4*)&D[(size_t)(j0 + p) * DIM + i0 + cx] = o;
        }
    }
}

// vout[row] = sum_j M[row][j] * (vin ? vin[j] : 1), M bf16 symmetric.
__global__ __launch_bounds__(256)
void mv_bf16(const unsigned short* __restrict__ M, const float* __restrict__ vin,
             float* __restrict__ vout) {
    int m = blockIdx.y;
    const unsigned short* A = M + (size_t)m * MSZ;
    int wv = threadIdx.x >> 6, lane = threadIdx.x & 63;
    int row = blockIdx.x * 4 + wv;
    const unsigned short* a = A + (size_t)row * DIM;
    float s = 0.f;
    if (vin) {
        const float* v = vin + m * DIM;
        for (int j = lane; j < DIM; j += 64) s += bf2f(a[j]) * v[j];
    } else {
        for (int j = lane; j < DIM; j += 64) s += bf2f(a[j]);
    }
    for (int off = 32; off; off >>= 1) s += __shfl_down(s, off);
    if (lane == 0) vout[m * DIM + row] = s;
}

// u[m][row] = sum_d f[row][d] * w[m][d]   (fp32, one wave per row)
__global__ __launch_bounds__(256)
void rownorm_k(const float* __restrict__ f0, const float* __restrict__ f1,
               const float* __restrict__ f2, const float* __restrict__ w,
               float* __restrict__ u) {
    int m = blockIdx.y;
    const float* f = (m == 0) ? f0 : (m == 1 ? f1 : f2);
    int wv = threadIdx.x >> 6, lane = threadIdx.x & 63;
    int row = blockIdx.x * 4 + wv;
    const float* a = f + (size_t)row * DIM;
    const float* ww = w + m * DIM;
    float s = 0.f;
#pragma unroll
    for (int it = 0; it < 4; ++it) {
        int d = (it * 64 + lane) * 4;
        float4 av = *(const float4*)&a[d];
        float4 bv = *(const float4*)&ww[d];
        s += av.x * bv.x + av.y * bv.y + av.z * bv.z + av.w * bv.w;
    }
    for (int off = 32; off; off >>= 1) s += __shfl_down(s, off);
    if (lane == 0) u[m * NROW + row] = s;
}

// lam[m] = |u_m|^2 / |w_m|^2 ; out = lam0 + 0.5*(lam1+lam2)
__global__ __launch_bounds__(1024)
void final_k(const float* __restrict__ u, const float* __restrict__ w,
             float* __restrict__ out) {
    __shared__ float red[1024];
    int tid = threadIdx.x;
    float lam[3];
    for (int m = 0; m < 3; ++m) {
        float s = 0.f;
        for (int i = tid; i < NROW; i += 1024) { float x = u[m * NROW + i]; s += x * x; }
        red[tid] = s; __syncthreads();
        for (int off = 512; off; off >>= 1) {
            if (tid < off) red[tid] += red[tid + off];
            __syncthreads();
        }
        float num = red[0]; __syncthreads();
        s = 0.f;
        for (int i = tid; i < DIM; i += 1024) { float x = w[m * DIM + i]; s += x * x; }
        red[tid] = s; __syncthreads();
        for (int off = 512; off; off >>= 1) {
            if (tid < off) red[tid] += red[tid + off];
            __syncthreads();
        }
        lam[m] = num / red[0]; __syncthreads();
    }
    if (tid == 0) out[0] = lam[0] + 0.5f * (lam[1] + lam[2]);
}

extern "C" void kernel_launch(void* const* d_in, const int* in_sizes, int n_in,
                              void* d_out, int out_size, void* d_ws, size_t ws_size,
                              hipStream_t stream) {
    const float* f0 = (const float*)d_in[0];
    const float* f1 = (const float*)d_in[1];
    const float* f2 = (const float*)d_in[2];

    char* base = (char*)d_ws;
    unsigned short* ft = (unsigned short*)base;                   // 48 MB bf16 f^T x3
    unsigned short* P  = (unsigned short*)(base + 50331648);      // 6 MB bf16 M x3
    float* G32 = (float*)(base + 56623104);                       // 7.08 MB packed-upper fp32
    unsigned short* Q  = (unsigned short*)(base + 56623104);      // overlays G32 (dead after convert)
    float* trbuf = (float*)(base + 63700992);                     // 64 floats
    float* v = (float*)(base + 63701248);                         // 3*1024
    float* w = v + 3 * DIM;                                       // 3*1024
    float* u = w + 3 * DIM;                                       // 3*8192

    // zero G32 (packed, 1769472 floats) + trbuf (64 floats) in one pass
    zero_k<<<1729, 256, 0, stream>>>(G32, 442384);

    dim3 gt(DIM / 64, NROW / 64, 3);
    tconv_k<<<gt, 256, 0, stream>>>(f0, f1, f2, ft);

    // G = ft ft' (K=8192), split-K x4, upper tiles, atomic fp32 accumulate
    syrk_sk<<<dim3(36, 4, 3), 256, 0, stream>>>(ft, (size_t)DIM * NROW, NROW, G32);
    // packed fp32 -> full bf16 P + trace
    convert_k<<<dim3(36, 1, 3), 256, 0, stream>>>(G32, trbuf, P);

    unsigned short* cur = P;
    unsigned short* nxt = Q;
    for (int s = 0; s < NS; ++s) {
        sq64<<<dim3(136, 1, 3), 256, 0, stream>>>(cur, trbuf + s * 3,
                                                  trbuf + (s + 1) * 3, nxt);
        unsigned short* t2 = cur; cur = nxt; nxt = t2;
    }

    dim3 b(256, 1, 1);
    dim3 gm(DIM / 4, 3, 1);
    mv_bf16<<<gm, b, 0, stream>>>(cur, nullptr, v);   // v = M*1
    mv_bf16<<<gm, b, 0, stream>>>(cur, v, w);         // w = M*v (polish)

    dim3 gr(NROW / 4, 3, 1);
    rownorm_k<<<gr, b, 0, stream>>>(f0, f1, f2, w, u);  // u = f*w
    final_k<<<1, 1024, 0, stream>>>(u, w, (float*)d_out);
}